// Round 3
// baseline (280.586 us; speedup 1.0000x reference)
//
#include <hip/hip_runtime.h>
#include <hip/hip_bf16.h>

#define NMODELS 64
#define BBATCH  4096
#define IN_DIM  64
#define H_DIM   256

typedef __attribute__((ext_vector_type(8))) short short8;
typedef __attribute__((ext_vector_type(4))) float floatx4;
typedef __attribute__((ext_vector_type(4))) unsigned int uint4v;
typedef __attribute__((ext_vector_type(2))) unsigned int uint2v;

__device__ __forceinline__ unsigned short f2bf(float f) {   // prep only
    unsigned int u = __builtin_bit_cast(unsigned int, f);
    return (unsigned short)((u + 0x8000u) >> 16);
}
// packed fp32x2 -> bf16x2 (v_cvt_pk_bf16_f32 on gfx950), RNE
__device__ __forceinline__ unsigned int pkbf(float a, float b) {
    __hip_bfloat162 h = __float22bfloat162_rn(make_float2(a, b));
    unsigned int u;
    __builtin_memcpy(&u, &h, 4);
    return u;
}

// Transpose+cvt: W1 [M][64][256]->w1t [M][256][64] bf16 (blocks 0..255)
//                W2 [M][256][256]->w2t [M][256][256] bf16 (blocks 256..1279)
__global__ __launch_bounds__(256) void prep_weights(const float* __restrict__ W1,
                                                    const float* __restrict__ W2,
                                                    unsigned short* __restrict__ w1t,
                                                    unsigned short* __restrict__ w2t) {
    __shared__ float lds[64][65];
    const int bid = blockIdx.x;
    const float* src;
    unsigned short* dst;
    int K, N, m, kb, nb;
    if (bid < 256) {
        m = bid >> 2; kb = 0; nb = bid & 3; K = IN_DIM; N = H_DIM;
        src = W1; dst = w1t;
    } else {
        int t = bid - 256;
        m = t >> 4; kb = (t >> 2) & 3; nb = t & 3; K = H_DIM; N = H_DIM;
        src = W2; dst = w2t;
    }
    const float* s = src + ((size_t)m * K + (size_t)kb * 64) * N + nb * 64;
    const int tid = threadIdx.x;
    const int r = tid >> 4, c4 = (tid & 15) * 4;
#pragma unroll
    for (int p = 0; p < 4; ++p) {
        int row = p * 16 + r;                      // k-local 0..63
        float4 v = *(const float4*)(s + (size_t)row * N + c4);
        lds[row][c4] = v.x; lds[row][c4 + 1] = v.y;
        lds[row][c4 + 2] = v.z; lds[row][c4 + 3] = v.w;
    }
    __syncthreads();
    unsigned short* dbase = dst + ((size_t)m * N + (size_t)nb * 64) * K + kb * 64;
    const int j = tid & 7;                         // k-chunk 0..7
#pragma unroll
    for (int it = 0; it < 2; ++it) {
        int n = it * 32 + (tid >> 3);              // n-local 0..63
        unsigned short tmp[8];
#pragma unroll
        for (int e = 0; e < 8; ++e) tmp[e] = f2bf(lds[j * 8 + e][n]);
        *(short8*)(dbase + (size_t)n * K + j * 8) = *(const short8*)tmp;
    }
}

__device__ __forceinline__ void loadx(const float* __restrict__ xp0, int c16, int q,
                                      float4 (&xr)[4][2][2]) {
#pragma unroll
    for (int rb = 0; rb < 4; ++rb)
#pragma unroll
        for (int kb = 0; kb < 2; ++kb) {
            const float* xp = xp0 + (rb * 16 + c16) * IN_DIM + kb * 32 + q * 8;
            xr[rb][kb][0] = *(const float4*)xp;
            xr[rb][kb][1] = *(const float4*)(xp + 4);
        }
}

__device__ __forceinline__ void cvtx(const float4 (&xr)[4][2][2], short8 (&axd)[4][2]) {
#pragma unroll
    for (int rb = 0; rb < 4; ++rb)
#pragma unroll
        for (int kb = 0; kb < 2; ++kb) {
            const float4 v0 = xr[rb][kb][0], v1 = xr[rb][kb][1];
            uint4v u;
            u[0] = pkbf(v0.x, v0.y); u[1] = pkbf(v0.z, v0.w);
            u[2] = pkbf(v1.x, v1.y); u[3] = pkbf(v1.z, v1.w);
            axd[rb][kb] = __builtin_bit_cast(short8, u);
        }
}

// Persistent fused 3-layer MLP. Grid = 512 WGs (2/CU), each WG loops over
// 4 consecutive tile-pairs (128 rows each) of ONE model m = blockIdx>>3.
// T=2 tiles per iteration (proven best shape: 101us vs T=1's 131us —
// per-WG amortization beats occupancy in this regime). Persistence adds:
//  - loop-invariant biases/pointers, W1/W2 L1/L2-hot across iterations
//  - cross-iteration x pipeline: next-t0 x loads issued in phase-2 kb==6
//    (behind all bv loads, no vmcnt drain), cvt'd during phase 3; next-t1
//    issued at phase-3 so its HBM latency hides under shfl-reduce + out.
// Reg peak ~ acc 64 AGPR + bv 48 + xr 64 + misc ~ 220 unified <= 256 (2 w/SIMD).
__global__ __launch_bounds__(256, 2) void mlp_fused(
    const float* __restrict__ xs,
    const unsigned short* __restrict__ w1t,   // [M][H][IN] bf16
    const float* __restrict__ b1,
    const unsigned short* __restrict__ w2t,   // [M][H][H] bf16 (n-major)
    const float* __restrict__ b2,
    const float* __restrict__ w3,             // [M][H]
    const float* __restrict__ b3,             // [M]
    float* __restrict__ out)                  // [M][B]
{
    __shared__ unsigned short h1s[2][64 * 256];   // 64 KB
    float* red = (float*)&h1s[0][0];              // phase-3 overlay (behind barrier)

    const int p      = blockIdx.x;                // 0..511
    const int m      = p >> 3;
    const int tpbase = (p & 7) * 4;               // tile-pairs tpbase..tpbase+3
    const int tid  = threadIdx.x;
    const int w    = tid >> 6;
    const int lane = tid & 63;
    const int q    = lane >> 4;
    const int c16  = lane & 15;
    const int sw   = c16 & 7;

    // loop-invariant loads (latency hidden behind prologue x stall)
    floatx4 b1v = *(const floatx4*)(b1 + m * H_DIM + w * 64 + c16 * 4);
    floatx4 b2v = *(const floatx4*)(b2 + m * H_DIM + w * 64 + c16 * 4);
    floatx4 w3v = *(const floatx4*)(w3 + m * H_DIM + w * 64 + c16 * 4);
    const float b3v = b3[m];

    const unsigned short* w1p = w1t + (size_t)m * (H_DIM * IN_DIM)
                                + (w * 64 + c16 * 4) * IN_DIM + q * 8;
    const unsigned short* w2p = w2t + (size_t)m * (H_DIM * H_DIM)
                                + (w * 64 + c16 * 4) * H_DIM + q * 8;
    const float* xbase = xs + (size_t)m * BBATCH * IN_DIM;

    float4 xr[4][2][2];
    short8 ax[2][4][2];

    // prologue: chunk 0 — t0 load+cvt (one cold HBM stall), then issue t1
    {
        const float* x0 = xbase + (size_t)(tpbase * 128) * IN_DIM;
        loadx(x0, c16, q, xr);
        cvtx(xr, ax[0]);
        loadx(x0 + 64 * IN_DIM, c16, q, xr);
    }

    floatx4 acc[2][4][4];
    short8 bv[3][4];

#pragma unroll 1
    for (int i = 0; i < 4; ++i) {
        // head: finish t1 (loads issued last phase-3 / prologue, long landed)
        cvtx(xr, ax[1]);

        // ---------------- Phase 1: h1[t] = relu(x[t] @ W1 + b1) ----------------
#pragma unroll
        for (int t = 0; t < 2; ++t)
#pragma unroll
            for (int rb = 0; rb < 4; ++rb)
#pragma unroll
                for (int nb = 0; nb < 4; ++nb)
                    acc[t][rb][nb] = (floatx4){0.f, 0.f, 0.f, 0.f};
        {
            short8 bw[2][4];                      // W1 frags (L1/L2-hot after i=0)
#pragma unroll
            for (int kb = 0; kb < 2; ++kb)
#pragma unroll
                for (int nb = 0; nb < 4; ++nb)
                    bw[kb][nb] = *(const short8*)(w1p + nb * IN_DIM + kb * 32);
#pragma unroll
            for (int t = 0; t < 2; ++t)
#pragma unroll
                for (int kb = 0; kb < 2; ++kb)
#pragma unroll
                    for (int nb = 0; nb < 4; ++nb)
#pragma unroll
                        for (int rb = 0; rb < 4; ++rb)
                            acc[t][rb][nb] = __builtin_amdgcn_mfma_f32_16x16x32_bf16(
                                ax[t][rb][kb], bw[kb][nb], acc[t][rb][nb], 0, 0, 0);
        }

        // Prefetch phase-2 B slots kb=0,1 (h1-independent): overlaps epilogue+barrier
#pragma unroll
        for (int nb = 0; nb < 4; ++nb) bv[0][nb] = *(const short8*)(w2p + nb * H_DIM + 0 * 32);
#pragma unroll
        for (int nb = 0; nb < 4; ++nb) bv[1][nb] = *(const short8*)(w2p + nb * H_DIM + 1 * 32);

        {   // epilogue: bias+relu+packed cvt, 8B ds_write, 16B-chunk XOR swizzle
#pragma unroll
            for (int t = 0; t < 2; ++t)
#pragma unroll
                for (int rb = 0; rb < 4; ++rb)
#pragma unroll
                    for (int r = 0; r < 4; ++r) {
                        float v0 = fmaxf(acc[t][rb][0][r] + b1v[0], 0.f);
                        float v1 = fmaxf(acc[t][rb][1][r] + b1v[1], 0.f);
                        float v2 = fmaxf(acc[t][rb][2][r] + b1v[2], 0.f);
                        float v3 = fmaxf(acc[t][rb][3][r] + b1v[3], 0.f);
                        uint2v u2; u2[0] = pkbf(v0, v1); u2[1] = pkbf(v2, v3);
                        int row = rb * 16 + q * 4 + r;
                        int chunk = (w * 8 + (c16 >> 1)) ^ (row & 7);
                        *(uint2v*)((char*)&h1s[t][0] + row * 512 + chunk * 16 + (c16 & 1) * 8) = u2;
                    }
        }
        __syncthreads();

        // ---------------- Phase 2: h2[t] = relu(h1[t] @ W2 + b2); pipelined B ----
#pragma unroll
        for (int t = 0; t < 2; ++t)
#pragma unroll
            for (int rb = 0; rb < 4; ++rb)
#pragma unroll
                for (int nb = 0; nb < 4; ++nb)
                    acc[t][rb][nb] = (floatx4){0.f, 0.f, 0.f, 0.f};

#pragma unroll
        for (int kb = 0; kb < 8; ++kb) {
            const int cur = kb % 3;
            const int pre = (kb + 2) % 3;
            if (kb < 6) {                         // keep depth-2 in flight
#pragma unroll
                for (int nb = 0; nb < 4; ++nb)
                    bv[pre][nb] = *(const short8*)(w2p + nb * H_DIM + (kb + 2) * 32);
            }
            if (kb == 6 && i < 3) {               // next-chunk t0 x loads, behind all bv
                const float* xn = xbase + (size_t)((tpbase + i + 1) * 128) * IN_DIM;
                loadx(xn, c16, q, xr);
            }
            short8 av[2][4];
#pragma unroll
            for (int t = 0; t < 2; ++t)
#pragma unroll
                for (int rb = 0; rb < 4; ++rb)
                    av[t][rb] = *(const short8*)((char*)&h1s[t][0] + (rb * 16 + c16) * 512
                                                 + (((kb * 4 + q) ^ sw) * 16));
#pragma unroll
            for (int nb = 0; nb < 4; ++nb)
#pragma unroll
                for (int t = 0; t < 2; ++t)
#pragma unroll
                    for (int rb = 0; rb < 4; ++rb)
                        acc[t][rb][nb] = __builtin_amdgcn_mfma_f32_16x16x32_bf16(
                            av[t][rb], bv[cur][nb], acc[t][rb][nb], 0, 0, 0);
        }

        // ---------------- Phase 3: out = h2 @ W3 + b3 (OUT=1), shfl reduce ------
        float pp[2][4][4];
#pragma unroll
        for (int t = 0; t < 2; ++t)
#pragma unroll
            for (int rb = 0; rb < 4; ++rb)
#pragma unroll
                for (int r = 0; r < 4; ++r) pp[t][rb][r] = 0.f;
#pragma unroll
        for (int t = 0; t < 2; ++t)
#pragma unroll
            for (int rb = 0; rb < 4; ++rb)
#pragma unroll
                for (int nb = 0; nb < 4; ++nb)
#pragma unroll
                    for (int r = 0; r < 4; ++r) {
                        float v = fmaxf(acc[t][rb][nb][r] + b2v[nb], 0.f);
                        pp[t][rb][r] += v * w3v[nb];
                    }

        if (i < 3) {   // finish next-t0 cvt (loads from kb==6), then issue next-t1;
                       // t1 HBM latency hides under the shfl tree + out write
            cvtx(xr, ax[0]);
            const float* xn = xbase + (size_t)((tpbase + i + 1) * 128) * IN_DIM;
            loadx(xn + 64 * IN_DIM, c16, q, xr);
        }

#pragma unroll
        for (int off = 1; off < 16; off <<= 1)
#pragma unroll
            for (int t = 0; t < 2; ++t)
#pragma unroll
                for (int rb = 0; rb < 4; ++rb)
#pragma unroll
                    for (int r = 0; r < 4; ++r)
                        pp[t][rb][r] += __shfl_xor(pp[t][rb][r], off);

        __syncthreads();               // all h1s reads done -> overlay red
        if (c16 == 0) {
#pragma unroll
            for (int t = 0; t < 2; ++t)
#pragma unroll
                for (int rb = 0; rb < 4; ++rb)
#pragma unroll
                    for (int r = 0; r < 4; ++r)
                        red[t * 256 + w * 64 + rb * 16 + q * 4 + r] = pp[t][rb][r];
        }
        __syncthreads();
        if (tid < 128) {
            int t = tid >> 6, rr = tid & 63;
            const float* rt = red + t * 256;
            float s = rt[rr] + rt[64 + rr] + rt[128 + rr] + rt[192 + rr] + b3v;
            out[(size_t)m * BBATCH + (tpbase + i) * 128 + tid] = s;
        }
        __syncthreads();               // red reads done before next epilogue writes
    }
}

extern "C" void kernel_launch(void* const* d_in, const int* in_sizes, int n_in,
                              void* d_out, int out_size, void* d_ws, size_t ws_size,
                              hipStream_t stream) {
    const float* xs = (const float*)d_in[0];
    const float* W1 = (const float*)d_in[1];
    const float* b1 = (const float*)d_in[2];
    const float* W2 = (const float*)d_in[3];
    const float* b2 = (const float*)d_in[4];
    const float* W3 = (const float*)d_in[5];
    const float* b3 = (const float*)d_in[6];
    float* out = (float*)d_out;

    unsigned short* w1t = (unsigned short*)d_ws;                    // 2 MB
    unsigned short* w2t = w1t + (size_t)NMODELS * H_DIM * IN_DIM;   // 8.4 MB

    prep_weights<<<256 + NMODELS * 16, 256, 0, stream>>>(W1, W2, w1t, w2t);
    mlp_fused<<<NMODELS * 8, 256, 0, stream>>>(xs, w1t, b1, w2t, b2, W3, b3, out);
}